// Round 6
// baseline (711.006 us; speedup 1.0000x reference)
//
#include <hip/hip_runtime.h>
#include <stdint.h>

typedef unsigned int u32;
typedef unsigned long long u64;
typedef __attribute__((ext_vector_type(4))) short short4v;
typedef __attribute__((ext_vector_type(8))) short short8;
typedef __attribute__((ext_vector_type(16))) float f32x16;

#define DEVI __device__ __forceinline__

constexpr int PRE_K = 1000;
constexpr int CAP = 8192;

// workspace layout (bytes)
constexpr size_t WF_OFF    = 0;         // frag-swizzled split weights: 3*4*72*1024 = 884736
constexpr size_t HIST_OFF  = 884736;    // 2*4096 u32 = 32768
constexpr size_t CNT_OFF   = 917504;    // 2 u32 (+pad)
constexpr size_t CAND_OFF  = 917632;    // 2*8192 u64 = 131072 -> 1048704
constexpr size_t MASK_OFF  = 1088768;   // 2*1024*16 u64 = 262144 -> 1350912
constexpr size_t SCARR_OFF = 1350912;   // 2*65536 f32 = 524288 -> 1875200
constexpr size_t WS_NEED   = 1875200;

constexpr size_t KB_OFF = 655360;   // kept_boxes offset in d_out (floats)
constexpr size_t KS_OFF = 657408;   // kept_scores offset in d_out (floats)

DEVI u32 fkey(float f) {
  u32 u = __float_as_uint(f);
  return (u & 0x80000000u) ? ~u : (u | 0x80000000u);
}

DEVI u64 shfl64(u64 v, int src) {
  int lo = __shfl((int)(u32)v, src, 64);
  int hi = __shfl((int)(u32)(v >> 32), src, 64);
  return ((u64)(u32)hi << 32) | (u64)(u32)lo;
}

// RNE f32 -> bf16 bits
DEVI u32 rne16(u32 u) { return (u + 0x7FFFu + ((u >> 16) & 1u)) >> 16; }

// ---- W_conv (co,ci,3,3) -> frag-order split-bf16 weights; also zero hist/cnt ----
// k = tap*128 + ci ; frag_id = (s*4 + (co>>5))*72 + (k>>4) ; slot = ((k>>3)&1)*32 + (co&31)
__global__ void wsplitk(const float* __restrict__ wc, float* __restrict__ wf,
                        u32* __restrict__ hist, u32* __restrict__ cnt) {
  int j = blockIdx.x * 256 + threadIdx.x;
  if (j < 8192) hist[j] = 0;
  if (j < 2) cnt[j] = 0;
  if (j >= 18432) return;
  int co = j / 144;
  int koct = j % 144;          // 8-element k group
  short8 h8, m8, l8;
#pragma unroll
  for (int jj = 0; jj < 8; ++jj) {
    int kk = koct * 8 + jj;
    int tap = kk >> 7, ci = kk & 127;
    float v = wc[(co * 128 + ci) * 9 + tap];
    u32 u0 = __float_as_uint(v);
    u32 hb = rne16(u0);
    float r1 = v - __uint_as_float(hb << 16);
    u32 mb = rne16(__float_as_uint(r1));
    float r2 = r1 - __uint_as_float(mb << 16);
    u32 lb = rne16(__float_as_uint(r2));
    h8[jj] = (short)hb; m8[jj] = (short)mb; l8[jj] = (short)lb;
  }
  int slot = ((koct & 1) << 5) + (co & 31);
  int kg = koct >> 1;
  int cblk = co >> 5;
  char* base = (char*)wf;
  *(short8*)(base + ((size_t)((0 * 4 + cblk) * 72 + kg) * 64 + slot) * 16) = h8;
  *(short8*)(base + ((size_t)((1 * 4 + cblk) * 72 + kg) * 64 + slot) * 16) = m8;
  *(short8*)(base + ((size_t)((2 * 4 + cblk) * 72 + kg) * 64 + slot) * 16) = l8;
}

// ---- fused split-bf16 MFMA conv3x3 + bias + relu + heads + decode + hist ----
// LDS: 3 bf16 planes [10][18][20] per 16-ci chunk (split once at staging).
__global__ __launch_bounds__(256, 4) void convk(
    const float* __restrict__ x, const float* __restrict__ wf,
    const float* __restrict__ bconv,
    const float* __restrict__ woff, const float* __restrict__ boff,
    const float* __restrict__ wlog, const float* __restrict__ blog,
    const int* __restrict__ ihp, const int* __restrict__ iwp,
    float* __restrict__ out, u32* __restrict__ hist, float* __restrict__ scarr)
{
  __shared__ union {
    unsigned short pl[3 * 3600];   // [s][hh][ww][ci pad 20] = 21600 B
    float tq[32][132];             // epilogue quadrant = 16896 B
  } sm;

  const int tid = threadIdx.x;
  const int l = tid & 63, wv = tid >> 6;
  const int mhalf = wv >> 1, nhalf = wv & 1;
  const int lm = l & 31, lg = l >> 5;
  const int bx = blockIdx.x, by = blockIdx.y, n = blockIdx.z;

  f32x16 acc[2][2];
#pragma unroll
  for (int mi = 0; mi < 2; ++mi)
#pragma unroll
    for (int ni = 0; ni < 2; ++ni)
#pragma unroll
      for (int q = 0; q < 16; ++q) acc[mi][ni][q] = 0.f;

  const char* wfb = (const char*)wf;

#pragma unroll 1
  for (int cc = 0; cc < 8; ++cc) {
    __syncthreads();
    // stage + split 16 ci x 10 h x 18 w
    const float* xbase = x + ((size_t)n * 128 + cc * 16) * 65536;
    for (int e = tid; e < 2880; e += 256) {
      int ci = e / 180, rem = e % 180;
      int hh = rem / 18, ww = rem % 18;
      int gh = by * 8 + hh - 1, gw = bx * 16 + ww - 1;
      float v = 0.f;
      if ((unsigned)gh < 256u && (unsigned)gw < 256u)
        v = xbase[(size_t)ci * 65536 + gh * 256 + gw];
      u32 u0 = __float_as_uint(v);
      u32 hb = rne16(u0);
      float r1 = v - __uint_as_float(hb << 16);
      u32 mb = rne16(__float_as_uint(r1));
      float r2 = r1 - __uint_as_float(mb << 16);
      u32 lb = rne16(__float_as_uint(r2));
      int idx = (hh * 18 + ww) * 20 + ci;
      sm.pl[idx] = (unsigned short)hb;
      sm.pl[idx + 3600] = (unsigned short)mb;
      sm.pl[idx + 7200] = (unsigned short)lb;
    }
    __syncthreads();

#pragma unroll 1
    for (int tap = 0; tap < 9; ++tap) {
      int dy = tap / 3 - 1, dx = tap % 3 - 1;
      short8 Af[3][2];
#pragma unroll
      for (int mi = 0; mi < 2; ++mi) {
        int hh = mhalf * 4 + mi * 2 + (lm >> 4) + dy + 1;
        int ww = (lm & 15) + dx + 1;
        int base = (hh * 18 + ww) * 20 + lg * 8;
#pragma unroll
        for (int s = 0; s < 3; ++s) {
          short4v a0 = *(const short4v*)&sm.pl[s * 3600 + base];
          short4v a1 = *(const short4v*)&sm.pl[s * 3600 + base + 4];
          short8 v8 = {a0[0], a0[1], a0[2], a0[3], a1[0], a1[1], a1[2], a1[3]};
          Af[s][mi] = v8;
        }
      }
#pragma unroll
      for (int sb = 0; sb < 3; ++sb) {
        short8 Bf[2];
#pragma unroll
        for (int ni = 0; ni < 2; ++ni) {
          int fid = (sb * 4 + nhalf * 2 + ni) * 72 + tap * 8 + cc;
          Bf[ni] = *(const short8*)(wfb + ((size_t)fid * 64 + l) * 16);
        }
#pragma unroll
        for (int sa = 0; sa < 3 - sb; ++sa)
#pragma unroll
          for (int mi = 0; mi < 2; ++mi)
#pragma unroll
            for (int ni = 0; ni < 2; ++ni)
              acc[mi][ni] = __builtin_amdgcn_mfma_f32_32x32x16_bf16(
                  Af[sa][mi], Bf[ni], acc[mi][ni], 0, 0, 0);
      }
    }
  }

  // ---- epilogue: serialized (mhalf, r) quadrants through tq ----
  __syncthreads();
  const int ihv = ihp[0], iwv = iwp[0];
  float bcv[2];
  bcv[0] = bconv[nhalf * 64 + lm];
  bcv[1] = bconv[nhalf * 64 + 32 + lm];
  const int cq = l >> 4;
  const int pxl = (nhalf << 4) + (l & 15);
  const float scale = (float)iwv / 256.0f;

#pragma unroll 1
  for (int mh = 0; mh < 2; ++mh) {
#pragma unroll 1
    for (int r = 0; r < 2; ++r) {
      if (mh || r) __syncthreads();
      if (mhalf == mh) {
#pragma unroll
        for (int ni = 0; ni < 2; ++ni)
#pragma unroll
          for (int rg = 0; rg < 16; ++rg) {
            int row = (rg & 3) + ((rg >> 2) << 3) + ((l >> 5) << 2);
            sm.tq[row][(nhalf << 6) + (ni << 5) + lm] =
                fmaxf((r ? acc[1][ni][rg] : acc[0][ni][rg]) + bcv[ni], 0.f);
          }
      }
      __syncthreads();
      if (mhalf == mh) {
        float tv[32];
#pragma unroll
        for (int i = 0; i < 8; ++i) {
          float4 t4 = *(const float4*)&sm.tq[pxl][(cq << 5) + (i << 2)];
          tv[i * 4 + 0] = t4.x; tv[i * 4 + 1] = t4.y;
          tv[i * 4 + 2] = t4.z; tv[i * 4 + 3] = t4.w;
        }
        float s19[19];
#pragma unroll
        for (int o = 0; o < 19; ++o) {
          const float* wh = (o < 18) ? (woff + o * 128) : wlog;
          const float4* w4 = (const float4*)(wh + (cq << 5));
          float a0 = 0.f;
#pragma unroll
          for (int i = 0; i < 8; ++i) {
            float4 wv4 = w4[i];
            a0 = fmaf(tv[i * 4 + 0], wv4.x, a0);
            a0 = fmaf(tv[i * 4 + 1], wv4.y, a0);
            a0 = fmaf(tv[i * 4 + 2], wv4.z, a0);
            a0 = fmaf(tv[i * 4 + 3], wv4.w, a0);
          }
          s19[o] = a0;
        }
#pragma unroll
        for (int o = 0; o < 19; ++o) {
          s19[o] += __shfl_xor(s19[o], 16, 64);
          s19[o] += __shfl_xor(s19[o], 32, 64);
        }
        if (cq == 0) {
          int bpx = (mh << 6) + (r << 5) + pxl;
          int ph = bpx >> 4, pw = bpx & 15;
          int gh = by * 8 + ph, gw = bx * 16 + pw;
          float sc = s19[18] + blog[0];
          // xs_lin uses linspace(0,image_h-1,Wf) indexed by w; ys_lin uses image_w, indexed by h
          float xv = (float)((double)gw * ((double)(ihv - 1) / 255.0));
          float yv = (float)((double)gh * ((double)(iwv - 1) / 255.0));
          float mnx = __builtin_inff(), mny = __builtin_inff();
          float mxx = -__builtin_inff(), mxy = -__builtin_inff();
#pragma unroll
          for (int p = 0; p < 9; ++p) {
            float ox = expf((s19[2 * p] + boff[2 * p]) * scale) - 1.f + xv;
            float oy = expf((s19[2 * p + 1] + boff[2 * p + 1]) * scale) - 1.f + yv;
            float cx2 = fminf(fmaxf(ox, 0.f), (float)(iwv - 1));
            float cy2 = fminf(fmaxf(oy, 0.f), (float)(ihv - 1));
            mnx = fminf(mnx, cx2); mxx = fmaxf(mxx, cx2);
            mny = fminf(mny, cy2); mxy = fmaxf(mxy, cy2);
          }
          size_t pix = (size_t)n * 65536 + (size_t)gh * 256 + gw;
          float* rec = out + pix * 5;
          rec[0] = sc; rec[1] = mnx; rec[2] = mny; rec[3] = mxx; rec[4] = mxy;
          if (scarr) scarr[pix] = sc;
          atomicAdd(&hist[n * 4096 + (fkey(sc) >> 20)], 1u);
        }
      }
    }
  }
}

// ---- cutoff (redundant per block) + collect candidates >= cutoff ----
__global__ __launch_bounds__(256) void collectk(const float* __restrict__ outr,
                                                const float* __restrict__ scarr,
                                                const u32* __restrict__ hist,
                                                u32* __restrict__ cnt, u64* __restrict__ cand) {
  int e = blockIdx.x * 256 + threadIdx.x;
  int n = e >> 16;
  int t = threadIdx.x;
  __shared__ u32 pre[256];
  __shared__ u32 cutv;
  const u32* h = hist + n * 4096;
  u32 s0 = 0;
  for (int k = 0; k < 16; ++k) s0 += h[4095 - (t * 16 + k)];
  pre[t] = s0;
  __syncthreads();
  for (int off = 1; off < 256; off <<= 1) {
    u32 add = (t >= off) ? pre[t - off] : 0u;
    __syncthreads();
    pre[t] += add;
    __syncthreads();
  }
  u32 incl = pre[t], excl = incl - s0;
  if (incl >= (u32)PRE_K && excl < (u32)PRE_K) {
    u32 cum = excl;
    for (int k = 0; k < 16; ++k) {
      int b = 4095 - (t * 16 + k);
      cum += h[b];
      if (cum >= (u32)PRE_K) { cutv = ((u32)b) << 20; break; }
    }
  }
  __syncthreads();
  u32 cut = cutv;
  u32 pix = e & 65535;
  float sc = scarr ? scarr[e] : outr[((size_t)n * 65536 + pix) * 5];
  u32 key = fkey(sc);
  if (key >= cut) {
    u32 pos = atomicAdd(&cnt[n], 1u);
    if (pos < (u32)CAP)
      cand[(size_t)n * CAP + pos] = ((u64)key << 32) | (u64)(0xFFFFFFFFu - pix);
  }
}

// ---- fused rank-select + IoU masks + greedy NMS scan + output (1 block/image) ----
__global__ __launch_bounds__(1024) void rmfk(const u64* __restrict__ cand,
                                             const u32* __restrict__ cnt,
                                             const float* __restrict__ outr,
                                             u64* __restrict__ maskw,
                                             float* __restrict__ out) {
  int n = blockIdx.x;
  int t = threadIdx.x;
  struct Sel {
    float bx[PRE_K][4];            // 16000 B
    float lsc[1024];               // 4096 B
    unsigned short ordA[1024];     // 2048 B
    unsigned short ordB[1024];     // 2048 B
  };
  __shared__ union { u64 d[CAP]; Sel s; } u;

  // phase 1: load candidates
  u32 m = cnt[n]; if (m > (u32)CAP) m = CAP;
  for (int i = t; i < (int)m; i += 1024) u.d[i] = cand[(size_t)n * CAP + i];
  __syncthreads();
  // phase 2: ranks (order-invariant, exact ties by idx) into registers
  int rr[8]; u32 rpix[8]; int nri = 0;
  for (int i = t; i < (int)m; i += 1024) {
    u64 ki = u.d[i];
    u32 r = 0;
    for (u32 j = 0; j < m; ++j) r += (u.d[j] > ki) ? 1u : 0u;
    if (r < (u32)PRE_K) {
      rr[nri] = (int)r;
      rpix[nri] = 0xFFFFFFFFu - (u32)(ki & 0xFFFFFFFFull);
      ++nri;
    }
  }
  __syncthreads();
  // phase 3: init lsc, then fill bx/lsc by rank
  u.s.lsc[t] = -__builtin_inff();
  __syncthreads();
  for (int q = 0; q < nri; ++q) {
    int r = rr[q]; u32 pix = rpix[q];
    const float* rec = outr + ((size_t)n * 65536 + pix) * 5;
    float sc = rec[0];
    float b0 = rec[1], b1 = rec[2], b2 = rec[3], b3 = rec[4];
    bool valid = ((b2 - b0) >= 0.f) && ((b3 - b1) >= 0.f);
    u.s.lsc[r] = valid ? sc : -__builtin_inff();
    u.s.bx[r][0] = b0; u.s.bx[r][1] = b1; u.s.bx[r][2] = b2; u.s.bx[r][3] = b3;
  }
  __syncthreads();
  // phase 4: IoU suppression masks -> global
  {
    float x1 = 0.f, y1 = 0.f, x2 = 0.f, y2 = 0.f, ai = 0.f;
    if (t < PRE_K) {
      x1 = u.s.bx[t][0]; y1 = u.s.bx[t][1]; x2 = u.s.bx[t][2]; y2 = u.s.bx[t][3];
      ai = (x2 - x1) * (y2 - y1);
    }
    for (int w = 0; w < 16; ++w) {
      u64 accm = 0;
      if (t < PRE_K) {
        int j0 = max(t + 1, w * 64), j1 = min(PRE_K, w * 64 + 64);
        for (int j = j0; j < j1; ++j) {
          float u1 = u.s.bx[j][0], v1 = u.s.bx[j][1], u2 = u.s.bx[j][2], v2 = u.s.bx[j][3];
          float aj = (u2 - u1) * (v2 - v1);
          float iw = fminf(x2, u2) - fmaxf(x1, u1); iw = fmaxf(iw, 0.f);
          float ih = fminf(y2, v2) - fmaxf(y1, v1); ih = fmaxf(ih, 0.f);
          float inter = iw * ih;
          float iou = inter / (ai + aj - inter + 1e-9f);
          if (iou > 0.7f) accm |= (1ull << (j & 63));
        }
      }
      maskw[((size_t)n * 1024 + t) * 16 + w] = accm;
    }
  }
  __threadfence();
  __syncthreads();
  // phase 5: wave 0 — serial greedy scan (reg prefetch), partition, output
  if (t < 64) {
    int lane = t;
    u64 sup = 0;
#pragma unroll
    for (int c = 0; c < 16; ++c) {
      u64 b = __ballot(!(u.s.lsc[c * 64 + lane] > -__builtin_inff()));
      if (lane == c) sup = b;
    }
    const u64* gm = maskw + (size_t)n * 1024 * 16;
    u64 pre16[16];
#pragma unroll
    for (int d = 0; d < 16; ++d)
      pre16[d] = (lane < 16) ? gm[d * 16 + lane] : 0ull;

    for (int i0 = 0; i0 < 1024; i0 += 16) {
#pragma unroll
      for (int d = 0; d < 16; ++d) {
        int i = i0 + d;
        u64 mi = pre16[d];
        int nx = i + 16;
        pre16[d] = (nx < 1024 && lane < 16) ? gm[(size_t)nx * 16 + lane] : 0ull;
        int w = i >> 6;
        u64 sw = shfl64(sup, w);
        bool supbit = (sw >> (i & 63)) & 1ull;
        if (!supbit) sup |= mi;
      }
    }

    u64 ltm = (1ull << lane) - 1ull;
    u32 baseA = 0, baseB = 0;
    for (int c = 0; c < 16; ++c) {
      int i = c * 64 + lane;
      u64 sw = shfl64(sup, c);
      bool bit = (sw >> lane) & 1ull;
      bool vi = i < PRE_K;
      bool sf = vi && !bit && (u.s.lsc[vi ? i : 0] > -__builtin_inff());
      u64 mA = __ballot(sf);
      u64 mB = __ballot(vi && !sf);
      if (sf) u.s.ordA[baseA + __popcll(mA & ltm)] = (unsigned short)i;
      else if (vi) u.s.ordB[baseB + __popcll(mB & ltm)] = (unsigned short)i;
      baseA += (u32)__popcll(mA);
      baseB += (u32)__popcll(mB);
    }

    for (int r = 0; r < 4; ++r) {
      int k = r * 64 + lane;   // 0..255
      int fi; float v;
      if (k < (int)baseA) { fi = u.s.ordA[k]; v = u.s.lsc[fi]; }
      else { fi = u.s.ordB[k - baseA]; v = -__builtin_inff(); }
      float* kb = out + KB_OFF + ((size_t)n * 256 + k) * 4;
      kb[0] = u.s.bx[fi][0]; kb[1] = u.s.bx[fi][1];
      kb[2] = u.s.bx[fi][2]; kb[3] = u.s.bx[fi][3];
      out[KS_OFF + (size_t)n * 256 + k] = v;
    }
  }
}

extern "C" void kernel_launch(void* const* d_in, const int* in_sizes, int n_in,
                              void* d_out, int out_size, void* d_ws, size_t ws_size,
                              hipStream_t stream) {
  const float* x     = (const float*)d_in[0];
  const float* wc    = (const float*)d_in[1];
  const float* bconv = (const float*)d_in[2];
  const float* woff  = (const float*)d_in[3];
  const float* boff  = (const float*)d_in[4];
  const float* wlog  = (const float*)d_in[5];
  const float* blog  = (const float*)d_in[6];
  const int* ihp     = (const int*)d_in[7];
  const int* iwp     = (const int*)d_in[8];
  float* out = (float*)d_out;
  char* ws = (char*)d_ws;

  float* wf    = (float*)(ws + WF_OFF);
  u32* hist    = (u32*)(ws + HIST_OFF);
  u32* cnt     = (u32*)(ws + CNT_OFF);
  u64* cand    = (u64*)(ws + CAND_OFF);
  u64* maskw   = (u64*)(ws + MASK_OFF);
  float* scarr = (ws_size >= WS_NEED) ? (float*)(ws + SCARR_OFF) : nullptr;

  hipLaunchKernelGGL(wsplitk, dim3(72), dim3(256), 0, stream, wc, wf, hist, cnt);
  hipLaunchKernelGGL(convk, dim3(16, 32, 2), dim3(256), 0, stream,
                     x, wf, bconv, woff, boff, wlog, blog, ihp, iwp, out, hist, scarr);
  hipLaunchKernelGGL(collectk, dim3(512), dim3(256), 0, stream, out, scarr, hist, cnt, cand);
  hipLaunchKernelGGL(rmfk, dim3(2), dim3(1024), 0, stream, cand, cnt, out, maskw, out);
}

// Round 7
// 654.813 us; speedup vs baseline: 1.0858x; 1.0858x over previous
//
#include <hip/hip_runtime.h>
#include <stdint.h>

typedef unsigned int u32;
typedef unsigned long long u64;
typedef __attribute__((ext_vector_type(4))) short short4v;
typedef __attribute__((ext_vector_type(8))) short short8;
typedef __attribute__((ext_vector_type(16))) float f32x16;

#define DEVI __device__ __forceinline__

constexpr int PRE_K = 1000;
constexpr int CAP = 8192;

// workspace layout (bytes)
constexpr size_t WF_OFF    = 0;         // frag-swizzled split weights: 3*4*72*1024 = 884736
constexpr size_t HIST_OFF  = 884736;    // 2*4096 u32 = 32768
constexpr size_t CNT_OFF   = 917504;    // 2 u32 (+pad)
constexpr size_t CUT_OFF   = 917568;    // 2 u32 (+pad)
constexpr size_t CAND_OFF  = 917632;    // 2*8192 u64 = 131072 -> 1048704
constexpr size_t TB_OFF    = 1048704;   // 2*1000*4 f32 = 32000 -> 1080704
constexpr size_t SCS_OFF   = 1080704;   // 2*1000 f32 = 8000 -> 1088704
constexpr size_t MASK_OFF  = 1088768;   // 2*1024*16 u64 = 262144 -> 1350912
constexpr size_t SCARR_OFF = 1350912;   // 2*65536 f32 = 524288 -> 1875200
constexpr size_t WS_NEED   = 1875200;

constexpr size_t KB_OFF = 655360;   // kept_boxes offset in d_out (floats)
constexpr size_t KS_OFF = 657408;   // kept_scores offset in d_out (floats)

DEVI u32 fkey(float f) {
  u32 u = __float_as_uint(f);
  return (u & 0x80000000u) ? ~u : (u | 0x80000000u);
}

DEVI u64 shfl64(u64 v, int src) {
  int lo = __shfl((int)(u32)v, src, 64);
  int hi = __shfl((int)(u32)(v >> 32), src, 64);
  return ((u64)(u32)hi << 32) | (u64)(u32)lo;
}

// RNE f32 -> bf16 bits
DEVI u32 rne16(u32 u) { return (u + 0x7FFFu + ((u >> 16) & 1u)) >> 16; }

// ---- W_conv (co,ci,3,3) -> frag-order split-bf16 weights; also zero hist/cnt ----
// k = tap*128 + ci ; frag_id = (s*4 + (co>>5))*72 + (k>>4) ; slot = ((k>>3)&1)*32 + (co&31)
__global__ void wsplitk(const float* __restrict__ wc, float* __restrict__ wf,
                        u32* __restrict__ hist, u32* __restrict__ cnt) {
  int j = blockIdx.x * 256 + threadIdx.x;
  if (j < 8192) hist[j] = 0;
  if (j < 2) cnt[j] = 0;
  if (j >= 18432) return;
  int co = j / 144;
  int koct = j % 144;          // 8-element k group
  short8 h8, m8, l8;
#pragma unroll
  for (int jj = 0; jj < 8; ++jj) {
    int kk = koct * 8 + jj;
    int tap = kk >> 7, ci = kk & 127;
    float v = wc[(co * 128 + ci) * 9 + tap];
    u32 u0 = __float_as_uint(v);
    u32 hb = rne16(u0);
    float r1 = v - __uint_as_float(hb << 16);
    u32 mb = rne16(__float_as_uint(r1));
    float r2 = r1 - __uint_as_float(mb << 16);
    u32 lb = rne16(__float_as_uint(r2));
    h8[jj] = (short)hb; m8[jj] = (short)mb; l8[jj] = (short)lb;
  }
  int slot = ((koct & 1) << 5) + (co & 31);
  int kg = koct >> 1;
  int cblk = co >> 5;
  char* base = (char*)wf;
  *(short8*)(base + ((size_t)((0 * 4 + cblk) * 72 + kg) * 64 + slot) * 16) = h8;
  *(short8*)(base + ((size_t)((1 * 4 + cblk) * 72 + kg) * 64 + slot) * 16) = m8;
  *(short8*)(base + ((size_t)((2 * 4 + cblk) * 72 + kg) * 64 + slot) * 16) = l8;
}

// ---- fused split-bf16 MFMA conv3x3 + bias + relu + heads + decode + hist ----
// LDS: 3 bf16 planes [10][18][20] per 16-ci chunk (split once at staging).
// launch_bounds(256,2): unified VGPR+AGPR budget 256/thread -> no scratch spill
// (256,4 capped at 128 and spilled ~110MB to scratch in round 6).
__global__ __launch_bounds__(256, 2) void convk(
    const float* __restrict__ x, const float* __restrict__ wf,
    const float* __restrict__ bconv,
    const float* __restrict__ woff, const float* __restrict__ boff,
    const float* __restrict__ wlog, const float* __restrict__ blog,
    const int* __restrict__ ihp, const int* __restrict__ iwp,
    float* __restrict__ out, u32* __restrict__ hist, float* __restrict__ scarr)
{
  __shared__ union {
    unsigned short pl[3 * 3600];   // [s][hh][ww][ci pad 20] = 21600 B
    float tq[32][132];             // epilogue quadrant = 16896 B
  } sm;

  const int tid = threadIdx.x;
  const int l = tid & 63, wv = tid >> 6;
  const int mhalf = wv >> 1, nhalf = wv & 1;
  const int lm = l & 31, lg = l >> 5;
  const int bx = blockIdx.x, by = blockIdx.y, n = blockIdx.z;

  f32x16 acc[2][2];
#pragma unroll
  for (int mi = 0; mi < 2; ++mi)
#pragma unroll
    for (int ni = 0; ni < 2; ++ni)
#pragma unroll
      for (int q = 0; q < 16; ++q) acc[mi][ni][q] = 0.f;

  const char* wfb = (const char*)wf;

#pragma unroll 1
  for (int cc = 0; cc < 8; ++cc) {
    __syncthreads();
    // stage + split 16 ci x 10 h x 18 w
    const float* xbase = x + ((size_t)n * 128 + cc * 16) * 65536;
    for (int e = tid; e < 2880; e += 256) {
      int ci = e / 180, rem = e % 180;
      int hh = rem / 18, ww = rem % 18;
      int gh = by * 8 + hh - 1, gw = bx * 16 + ww - 1;
      float v = 0.f;
      if ((unsigned)gh < 256u && (unsigned)gw < 256u)
        v = xbase[(size_t)ci * 65536 + gh * 256 + gw];
      u32 u0 = __float_as_uint(v);
      u32 hb = rne16(u0);
      float r1 = v - __uint_as_float(hb << 16);
      u32 mb = rne16(__float_as_uint(r1));
      float r2 = r1 - __uint_as_float(mb << 16);
      u32 lb = rne16(__float_as_uint(r2));
      int idx = (hh * 18 + ww) * 20 + ci;
      sm.pl[idx] = (unsigned short)hb;
      sm.pl[idx + 3600] = (unsigned short)mb;
      sm.pl[idx + 7200] = (unsigned short)lb;
    }
    __syncthreads();

#pragma unroll 1
    for (int tap = 0; tap < 9; ++tap) {
      int dy = tap / 3 - 1, dx = tap % 3 - 1;
      short8 Af[3][2];
#pragma unroll
      for (int mi = 0; mi < 2; ++mi) {
        int hh = mhalf * 4 + mi * 2 + (lm >> 4) + dy + 1;
        int ww = (lm & 15) + dx + 1;
        int base = (hh * 18 + ww) * 20 + lg * 8;
#pragma unroll
        for (int s = 0; s < 3; ++s) {
          short4v a0 = *(const short4v*)&sm.pl[s * 3600 + base];
          short4v a1 = *(const short4v*)&sm.pl[s * 3600 + base + 4];
          short8 v8 = {a0[0], a0[1], a0[2], a0[3], a1[0], a1[1], a1[2], a1[3]};
          Af[s][mi] = v8;
        }
      }
#pragma unroll
      for (int sb = 0; sb < 3; ++sb) {
        short8 Bf[2];
#pragma unroll
        for (int ni = 0; ni < 2; ++ni) {
          int fid = (sb * 4 + nhalf * 2 + ni) * 72 + tap * 8 + cc;
          Bf[ni] = *(const short8*)(wfb + ((size_t)fid * 64 + l) * 16);
        }
#pragma unroll
        for (int sa = 0; sa < 3 - sb; ++sa)
#pragma unroll
          for (int mi = 0; mi < 2; ++mi)
#pragma unroll
            for (int ni = 0; ni < 2; ++ni)
              acc[mi][ni] = __builtin_amdgcn_mfma_f32_32x32x16_bf16(
                  Af[sa][mi], Bf[ni], acc[mi][ni], 0, 0, 0);
      }
    }
  }

  // ---- epilogue: serialized (mhalf, r) quadrants through tq ----
  __syncthreads();
  const int ihv = ihp[0], iwv = iwp[0];
  float bcv[2];
  bcv[0] = bconv[nhalf * 64 + lm];
  bcv[1] = bconv[nhalf * 64 + 32 + lm];
  const int cq = l >> 4;
  const int pxl = (nhalf << 4) + (l & 15);
  const float scale = (float)iwv / 256.0f;

#pragma unroll 1
  for (int mh = 0; mh < 2; ++mh) {
#pragma unroll 1
    for (int r = 0; r < 2; ++r) {
      if (mh || r) __syncthreads();
      if (mhalf == mh) {
#pragma unroll
        for (int ni = 0; ni < 2; ++ni)
#pragma unroll
          for (int rg = 0; rg < 16; ++rg) {
            int row = (rg & 3) + ((rg >> 2) << 3) + ((l >> 5) << 2);
            sm.tq[row][(nhalf << 6) + (ni << 5) + lm] =
                fmaxf((r ? acc[1][ni][rg] : acc[0][ni][rg]) + bcv[ni], 0.f);
          }
      }
      __syncthreads();
      if (mhalf == mh) {
        float tv[32];
#pragma unroll
        for (int i = 0; i < 8; ++i) {
          float4 t4 = *(const float4*)&sm.tq[pxl][(cq << 5) + (i << 2)];
          tv[i * 4 + 0] = t4.x; tv[i * 4 + 1] = t4.y;
          tv[i * 4 + 2] = t4.z; tv[i * 4 + 3] = t4.w;
        }
        float s19[19];
#pragma unroll
        for (int o = 0; o < 19; ++o) {
          const float* wh = (o < 18) ? (woff + o * 128) : wlog;
          const float4* w4 = (const float4*)(wh + (cq << 5));
          float a0 = 0.f;
#pragma unroll
          for (int i = 0; i < 8; ++i) {
            float4 wv4 = w4[i];
            a0 = fmaf(tv[i * 4 + 0], wv4.x, a0);
            a0 = fmaf(tv[i * 4 + 1], wv4.y, a0);
            a0 = fmaf(tv[i * 4 + 2], wv4.z, a0);
            a0 = fmaf(tv[i * 4 + 3], wv4.w, a0);
          }
          s19[o] = a0;
        }
#pragma unroll
        for (int o = 0; o < 19; ++o) {
          s19[o] += __shfl_xor(s19[o], 16, 64);
          s19[o] += __shfl_xor(s19[o], 32, 64);
        }
        if (cq == 0) {
          int bpx = (mh << 6) + (r << 5) + pxl;
          int ph = bpx >> 4, pw = bpx & 15;
          int gh = by * 8 + ph, gw = bx * 16 + pw;
          float sc = s19[18] + blog[0];
          // xs_lin uses linspace(0,image_h-1,Wf) indexed by w; ys_lin uses image_w, indexed by h
          float xv = (float)((double)gw * ((double)(ihv - 1) / 255.0));
          float yv = (float)((double)gh * ((double)(iwv - 1) / 255.0));
          float mnx = __builtin_inff(), mny = __builtin_inff();
          float mxx = -__builtin_inff(), mxy = -__builtin_inff();
#pragma unroll
          for (int p = 0; p < 9; ++p) {
            float ox = expf((s19[2 * p] + boff[2 * p]) * scale) - 1.f + xv;
            float oy = expf((s19[2 * p + 1] + boff[2 * p + 1]) * scale) - 1.f + yv;
            float cx2 = fminf(fmaxf(ox, 0.f), (float)(iwv - 1));
            float cy2 = fminf(fmaxf(oy, 0.f), (float)(ihv - 1));
            mnx = fminf(mnx, cx2); mxx = fmaxf(mxx, cx2);
            mny = fminf(mny, cy2); mxy = fmaxf(mxy, cy2);
          }
          size_t pix = (size_t)n * 65536 + (size_t)gh * 256 + gw;
          float* rec = out + pix * 5;
          rec[0] = sc; rec[1] = mnx; rec[2] = mny; rec[3] = mxx; rec[4] = mxy;
          if (scarr) scarr[pix] = sc;
          atomicAdd(&hist[n * 4096 + (fkey(sc) >> 20)], 1u);
        }
      }
    }
  }
}

// ---- find cutoff bin (rank PRE_K) ----
__global__ __launch_bounds__(256) void cutoffk(const u32* __restrict__ hist, u32* __restrict__ cut) {
  int n = blockIdx.x;
  const u32* h = hist + n * 4096;
  __shared__ u32 pre[256];
  int t = threadIdx.x;
  u32 s0 = 0;
  for (int k = 0; k < 16; ++k) s0 += h[4095 - (t * 16 + k)];
  pre[t] = s0;
  __syncthreads();
  for (int off = 1; off < 256; off <<= 1) {
    u32 add = (t >= off) ? pre[t - off] : 0u;
    __syncthreads();
    pre[t] += add;
    __syncthreads();
  }
  u32 incl = pre[t];
  u32 excl = incl - s0;
  if (incl >= (u32)PRE_K && excl < (u32)PRE_K) {
    u32 cum = excl;
    for (int k = 0; k < 16; ++k) {
      int b = 4095 - (t * 16 + k);
      cum += h[b];
      if (cum >= (u32)PRE_K) { cut[n] = ((u32)b) << 20; break; }
    }
  }
}

// ---- collect candidates >= cutoff (coalesced via scarr) ----
__global__ void collectk(const float* __restrict__ out, const float* __restrict__ scarr,
                         const u32* __restrict__ cut,
                         u32* __restrict__ cnt, u64* __restrict__ cand) {
  int e = blockIdx.x * 256 + threadIdx.x;
  int n = e >> 16;
  u32 pix = e & 65535;
  float sc = scarr ? scarr[e] : out[((size_t)n * 65536 + pix) * 5];
  u32 key = fkey(sc);
  if (key >= cut[n]) {
    u32 pos = atomicAdd(&cnt[n], 1u);
    if (pos < (u32)CAP)
      cand[(size_t)n * CAP + pos] = ((u64)key << 32) | (u64)(0xFFFFFFFFu - pix);
  }
}

// ---- O(m^2) rank selection of top-1000 (order-invariant, exact ties by idx) ----
__global__ __launch_bounds__(1024) void ranksel(const u64* __restrict__ cand, const u32* __restrict__ cnt,
                                                const float* __restrict__ out,
                                                float* __restrict__ tb, float* __restrict__ scs) {
  int n = blockIdx.x;
  int t = threadIdx.x;
  __shared__ u64 d[CAP];
  u32 m = cnt[n]; if (m > (u32)CAP) m = CAP;
  for (int i = t; i < (int)m; i += 1024) d[i] = cand[(size_t)n * CAP + i];
  __syncthreads();
  for (int i = t; i < (int)m; i += 1024) {
    u64 ki = d[i];
    u32 r = 0;
    for (u32 j = 0; j < m; ++j) r += (d[j] > ki) ? 1u : 0u;
    if (r < (u32)PRE_K) {
      u32 pix = 0xFFFFFFFFu - (u32)(ki & 0xFFFFFFFFull);
      const float* rec = out + ((size_t)n * 65536 + pix) * 5;
      float sc = rec[0];
      float b0 = rec[1], b1 = rec[2], b2 = rec[3], b3 = rec[4];
      bool valid = ((b2 - b0) >= 0.f) && ((b3 - b1) >= 0.f);
      scs[n * PRE_K + r] = valid ? sc : -__builtin_inff();
      float* tbp = tb + ((size_t)n * PRE_K + r) * 4;
      tbp[0] = b0; tbp[1] = b1; tbp[2] = b2; tbp[3] = b3;
    }
  }
}

// ---- pairwise IoU suppression bitmasks; grid (colchunk=16, n=2) ----
__global__ __launch_bounds__(1024) void maskk(const float* __restrict__ tb, u64* __restrict__ maskw) {
  int c = blockIdx.x;
  int n = blockIdx.y;
  int t = threadIdx.x;
  __shared__ float bx[PRE_K][4];
  for (int e = t; e < PRE_K * 4; e += 1024) ((float*)bx)[e] = tb[(size_t)n * PRE_K * 4 + e];
  __syncthreads();
  u64 accm = 0;
  if (t < PRE_K) {
    float x1 = bx[t][0], y1 = bx[t][1], x2 = bx[t][2], y2 = bx[t][3];
    float ai = (x2 - x1) * (y2 - y1);
    int j0 = max(t + 1, c * 64), j1 = min(PRE_K, c * 64 + 64);
    for (int j = j0; j < j1; ++j) {
      float u1 = bx[j][0], v1 = bx[j][1], u2 = bx[j][2], v2 = bx[j][3];
      float aj = (u2 - u1) * (v2 - v1);
      float iw = fminf(x2, u2) - fmaxf(x1, u1); iw = fmaxf(iw, 0.f);
      float ih = fminf(y2, v2) - fmaxf(y1, v1); ih = fmaxf(ih, 0.f);
      float inter = iw * ih;
      float iou = inter / (ai + aj - inter + 1e-9f);
      if (iou > 0.7f) accm |= (1ull << (j & 63));
    }
  }
  maskw[((size_t)n * 1024 + t) * 16 + c] = accm;
}

// ---- serial greedy scan (reg-prefetch from global) + stable partition ----
__global__ __launch_bounds__(64) void finalk(const u64* __restrict__ maskw,
                                             const float* __restrict__ scs,
                                             const float* __restrict__ tb,
                                             float* __restrict__ out) {
  int n = blockIdx.x;
  int lane = threadIdx.x;
  __shared__ float lsc[1024];
  __shared__ unsigned short ordA[1024];
  __shared__ unsigned short ordB[1024];
  for (int e = lane; e < 1024; e += 64)
    lsc[e] = (e < PRE_K) ? scs[n * PRE_K + e] : -__builtin_inff();
  __syncthreads();

  u64 sup = 0;
#pragma unroll
  for (int c = 0; c < 16; ++c) {
    u64 b = __ballot(!(lsc[c * 64 + lane] > -__builtin_inff()));
    if (lane == c) sup = b;
  }

  const u64* gm = maskw + (size_t)n * 1024 * 16;
  u64 pre[16];
#pragma unroll
  for (int d = 0; d < 16; ++d)
    pre[d] = (lane < 16) ? gm[d * 16 + lane] : 0ull;

  for (int i0 = 0; i0 < 1024; i0 += 16) {
#pragma unroll
    for (int d = 0; d < 16; ++d) {
      int i = i0 + d;
      u64 mi = pre[d];
      int nx = i + 16;
      pre[d] = (nx < 1024 && lane < 16) ? gm[(size_t)nx * 16 + lane] : 0ull;
      int w = i >> 6;
      u64 sw = shfl64(sup, w);
      bool supbit = (sw >> (i & 63)) & 1ull;
      if (!supbit) sup |= mi;
    }
  }

  u64 ltm = (1ull << lane) - 1ull;
  u32 baseA = 0, baseB = 0;
  for (int c = 0; c < 16; ++c) {
    int i = c * 64 + lane;
    u64 sw = shfl64(sup, c);
    bool bit = (sw >> lane) & 1ull;
    bool vi = i < PRE_K;
    bool sf = vi && !bit && (lsc[vi ? i : 0] > -__builtin_inff());
    u64 mA = __ballot(sf);
    u64 mB = __ballot(vi && !sf);
    if (sf) ordA[baseA + __popcll(mA & ltm)] = (unsigned short)i;
    else if (vi) ordB[baseB + __popcll(mB & ltm)] = (unsigned short)i;
    baseA += (u32)__popcll(mA);
    baseB += (u32)__popcll(mB);
  }
  __syncthreads();

  for (int r = 0; r < 4; ++r) {
    int k = r * 64 + lane;
    int fi; float v;
    if (k < (int)baseA) { fi = ordA[k]; v = lsc[fi]; }
    else { fi = ordB[k - baseA]; v = -__builtin_inff(); }
    const float* bp = tb + ((size_t)n * PRE_K + fi) * 4;
    float* kb = out + KB_OFF + ((size_t)n * 256 + k) * 4;
    kb[0] = bp[0]; kb[1] = bp[1]; kb[2] = bp[2]; kb[3] = bp[3];
    out[KS_OFF + (size_t)n * 256 + k] = v;
  }
}

extern "C" void kernel_launch(void* const* d_in, const int* in_sizes, int n_in,
                              void* d_out, int out_size, void* d_ws, size_t ws_size,
                              hipStream_t stream) {
  const float* x     = (const float*)d_in[0];
  const float* wc    = (const float*)d_in[1];
  const float* bconv = (const float*)d_in[2];
  const float* woff  = (const float*)d_in[3];
  const float* boff  = (const float*)d_in[4];
  const float* wlog  = (const float*)d_in[5];
  const float* blog  = (const float*)d_in[6];
  const int* ihp     = (const int*)d_in[7];
  const int* iwp     = (const int*)d_in[8];
  float* out = (float*)d_out;
  char* ws = (char*)d_ws;

  float* wf    = (float*)(ws + WF_OFF);
  u32* hist    = (u32*)(ws + HIST_OFF);
  u32* cnt     = (u32*)(ws + CNT_OFF);
  u32* cut     = (u32*)(ws + CUT_OFF);
  u64* cand    = (u64*)(ws + CAND_OFF);
  float* tb    = (float*)(ws + TB_OFF);
  float* scs   = (float*)(ws + SCS_OFF);
  u64* maskw   = (u64*)(ws + MASK_OFF);
  float* scarr = (ws_size >= WS_NEED) ? (float*)(ws + SCARR_OFF) : nullptr;

  hipLaunchKernelGGL(wsplitk, dim3(72), dim3(256), 0, stream, wc, wf, hist, cnt);
  hipLaunchKernelGGL(convk, dim3(16, 32, 2), dim3(256), 0, stream,
                     x, wf, bconv, woff, boff, wlog, blog, ihp, iwp, out, hist, scarr);
  hipLaunchKernelGGL(cutoffk, dim3(2), dim3(256), 0, stream, hist, cut);
  hipLaunchKernelGGL(collectk, dim3(512), dim3(256), 0, stream, out, scarr, cut, cnt, cand);
  hipLaunchKernelGGL(ranksel, dim3(2), dim3(1024), 0, stream, cand, cnt, out, tb, scs);
  hipLaunchKernelGGL(maskk, dim3(16, 2), dim3(1024), 0, stream, tb, maskw);
  hipLaunchKernelGGL(finalk, dim3(2), dim3(64), 0, stream, maskw, scs, tb, out);
}

// Round 11
// 609.925 us; speedup vs baseline: 1.1657x; 1.0736x over previous
//
#include <hip/hip_runtime.h>
#include <stdint.h>

typedef unsigned int u32;
typedef unsigned long long u64;
typedef __attribute__((ext_vector_type(4))) short short4v;
typedef __attribute__((ext_vector_type(8))) short short8;
typedef __attribute__((ext_vector_type(16))) float f32x16;

#define DEVI __device__ __forceinline__

constexpr int PRE_K = 1000;
constexpr int CAP = 8192;

// workspace layout (bytes)
constexpr size_t WF_OFF    = 0;         // frag-swizzled split weights: 3*4*72*1024 = 884736
constexpr size_t HIST_OFF  = 884736;    // 2*4096 u32 = 32768
constexpr size_t CNT_OFF   = 917504;    // 2 u32 (+pad)
constexpr size_t CUT_OFF   = 917568;    // 2 u32 (+pad)
constexpr size_t CAND_OFF  = 917632;    // 2*8192 u64 = 131072 -> 1048704
constexpr size_t TB_OFF    = 1048704;   // 2*1000*4 f32 = 32000 -> 1080704
constexpr size_t SCS_OFF   = 1080704;   // 2*1000 f32 = 8000 -> 1088704
constexpr size_t MASK_OFF  = 1088768;   // 2*1024*16 u64 = 262144 -> 1350912
constexpr size_t SCARR_OFF = 1350912;   // 2*65536 f32 = 524288 -> 1875200
constexpr size_t WS_NEED   = 1875200;

constexpr size_t KB_OFF = 655360;   // kept_boxes offset in d_out (floats)
constexpr size_t KS_OFF = 657408;   // kept_scores offset in d_out (floats)

DEVI u32 fkey(float f) {
  u32 u = __float_as_uint(f);
  return (u & 0x80000000u) ? ~u : (u | 0x80000000u);
}

DEVI u64 shfl64(u64 v, int src) {
  int lo = __shfl((int)(u32)v, src, 64);
  int hi = __shfl((int)(u32)(v >> 32), src, 64);
  return ((u64)(u32)hi << 32) | (u64)(u32)lo;
}

// RNE f32 -> bf16 bits
DEVI u32 rne16(u32 u) { return (u + 0x7FFFu + ((u >> 16) & 1u)) >> 16; }

// ---- W_conv (co,ci,3,3) -> frag-order split-bf16 weights; also zero hist/cnt ----
// k = tap*128 + ci ; frag_id = (s*4 + (co>>5))*72 + (k>>4) ; slot = ((k>>3)&1)*32 + (co&31)
__global__ void wsplitk(const float* __restrict__ wc, float* __restrict__ wf,
                        u32* __restrict__ hist, u32* __restrict__ cnt) {
  int j = blockIdx.x * 256 + threadIdx.x;
  if (j < 8192) hist[j] = 0;
  if (j < 2) cnt[j] = 0;
  if (j >= 18432) return;
  int co = j / 144;
  int koct = j % 144;          // 8-element k group
  short8 h8, m8, l8;
#pragma unroll
  for (int jj = 0; jj < 8; ++jj) {
    int kk = koct * 8 + jj;
    int tap = kk >> 7, ci = kk & 127;
    float v = wc[(co * 128 + ci) * 9 + tap];
    u32 u0 = __float_as_uint(v);
    u32 hb = rne16(u0);
    float r1 = v - __uint_as_float(hb << 16);
    u32 mb = rne16(__float_as_uint(r1));
    float r2 = r1 - __uint_as_float(mb << 16);
    u32 lb = rne16(__float_as_uint(r2));
    h8[jj] = (short)hb; m8[jj] = (short)mb; l8[jj] = (short)lb;
  }
  int slot = ((koct & 1) << 5) + (co & 31);
  int kg = koct >> 1;
  int cblk = co >> 5;
  char* base = (char*)wf;
  *(short8*)(base + ((size_t)((0 * 4 + cblk) * 72 + kg) * 64 + slot) * 16) = h8;
  *(short8*)(base + ((size_t)((1 * 4 + cblk) * 72 + kg) * 64 + slot) * 16) = m8;
  *(short8*)(base + ((size_t)((2 * 4 + cblk) * 72 + kg) * 64 + slot) * 16) = l8;
}

// ---- fused split-bf16 MFMA conv3x3 + bias + relu + heads + decode + hist ----
// Reg-staged double-buffer (T14): issue chunk cc+1's global loads BEFORE the
// MFMA phase of chunk cc (HBM latency hides under ~2600cy of MFMA+LDS); split +
// ds_write after the post-compute barrier. LDS stays single-buffered.
__global__ __launch_bounds__(256, 2) void convk(
    const float* __restrict__ x, const float* __restrict__ wf,
    const float* __restrict__ bconv,
    const float* __restrict__ woff, const float* __restrict__ boff,
    const float* __restrict__ wlog, const float* __restrict__ blog,
    const int* __restrict__ ihp, const int* __restrict__ iwp,
    float* __restrict__ out, u32* __restrict__ hist, float* __restrict__ scarr)
{
  __shared__ union {
    unsigned short pl[3 * 3600];   // [s][hh][ww][ci pad 20] = 21600 B
    float tq[32][132];             // epilogue quadrant = 16896 B
  } sm;

  const int tid = threadIdx.x;
  const int l = tid & 63, wv = tid >> 6;
  const int mhalf = wv >> 1, nhalf = wv & 1;
  const int lm = l & 31, lg = l >> 5;
  const int bx = blockIdx.x, by = blockIdx.y, n = blockIdx.z;

  f32x16 acc[2][2];
#pragma unroll
  for (int mi = 0; mi < 2; ++mi)
#pragma unroll
    for (int ni = 0; ni < 2; ++ni)
#pragma unroll
      for (int q = 0; q < 16; ++q) acc[mi][ni][q] = 0.f;

  const char* wfb = (const char*)wf;

  // staged regs for next chunk
  float stv[12];
  int stix[12];

  // ---- STAGE_ISSUE(chunk) : 12 predicated global loads into regs ----
#define STAGE_ISSUE(CC)                                                        \
  {                                                                            \
    const float* xbase = x + ((size_t)n * 128 + (CC) * 16) * 65536;            \
    _Pragma("unroll")                                                          \
    for (int k = 0; k < 12; ++k) {                                             \
      int e = tid + (k << 8);                                                  \
      float v = 0.f; int ix = -1;                                              \
      if (e < 2880) {                                                          \
        int ci = e / 180, rem = e % 180;                                       \
        int hh = rem / 18, ww = rem % 18;                                      \
        int gh = by * 8 + hh - 1, gw = bx * 16 + ww - 1;                       \
        if ((unsigned)gh < 256u && (unsigned)gw < 256u)                        \
          v = xbase[(size_t)ci * 65536 + gh * 256 + gw];                       \
        ix = (hh * 18 + ww) * 20 + ci;                                         \
      }                                                                        \
      stv[k] = v; stix[k] = ix;                                                \
    }                                                                          \
  }

  // ---- STAGE_WRITE : split once, write 3 bf16 planes to LDS ----
#define STAGE_WRITE()                                                          \
  {                                                                            \
    _Pragma("unroll")                                                          \
    for (int k = 0; k < 12; ++k) {                                             \
      if (stix[k] >= 0) {                                                      \
        float v = stv[k];                                                      \
        u32 u0 = __float_as_uint(v);                                           \
        u32 hb = rne16(u0);                                                    \
        float r1 = v - __uint_as_float(hb << 16);                              \
        u32 mb = rne16(__float_as_uint(r1));                                   \
        float r2 = r1 - __uint_as_float(mb << 16);                             \
        u32 lb = rne16(__float_as_uint(r2));                                   \
        sm.pl[stix[k]] = (unsigned short)hb;                                   \
        sm.pl[stix[k] + 3600] = (unsigned short)mb;                            \
        sm.pl[stix[k] + 7200] = (unsigned short)lb;                            \
      }                                                                        \
    }                                                                          \
  }

  // prologue: stage chunk 0
  STAGE_ISSUE(0);
  STAGE_WRITE();
  __syncthreads();

#pragma unroll 1
  for (int cc = 0; cc < 8; ++cc) {
    // issue next chunk's loads early — hide HBM latency under MFMA below
    if (cc < 7) STAGE_ISSUE(cc + 1);

#pragma unroll 1
    for (int tap = 0; tap < 9; ++tap) {
      int dy = tap / 3 - 1, dx = tap % 3 - 1;
      short8 Af[3][2];
#pragma unroll
      for (int mi = 0; mi < 2; ++mi) {
        int hh = mhalf * 4 + mi * 2 + (lm >> 4) + dy + 1;
        int ww = (lm & 15) + dx + 1;
        int base = (hh * 18 + ww) * 20 + lg * 8;
#pragma unroll
        for (int s = 0; s < 3; ++s) {
          short4v a0 = *(const short4v*)&sm.pl[s * 3600 + base];
          short4v a1 = *(const short4v*)&sm.pl[s * 3600 + base + 4];
          short8 v8 = {a0[0], a0[1], a0[2], a0[3], a1[0], a1[1], a1[2], a1[3]};
          Af[s][mi] = v8;
        }
      }
#pragma unroll
      for (int sb = 0; sb < 3; ++sb) {
        short8 Bf[2];
#pragma unroll
        for (int ni = 0; ni < 2; ++ni) {
          int fid = (sb * 4 + nhalf * 2 + ni) * 72 + tap * 8 + cc;
          Bf[ni] = *(const short8*)(wfb + ((size_t)fid * 64 + l) * 16);
        }
#pragma unroll
        for (int sa = 0; sa < 3 - sb; ++sa)
#pragma unroll
          for (int mi = 0; mi < 2; ++mi)
#pragma unroll
            for (int ni = 0; ni < 2; ++ni)
              acc[mi][ni] = __builtin_amdgcn_mfma_f32_32x32x16_bf16(
                  Af[sa][mi], Bf[ni], acc[mi][ni], 0, 0, 0);
      }
    }

    __syncthreads();               // all waves done reading LDS chunk cc
    if (cc < 7) {
      STAGE_WRITE();               // split + write chunk cc+1
      __syncthreads();             // LDS ready for next compute
    }
  }

  // ---- epilogue: serialized (mhalf, r) quadrants through tq ----
  __syncthreads();
  const int ihv = ihp[0], iwv = iwp[0];
  float bcv[2];
  bcv[0] = bconv[nhalf * 64 + lm];
  bcv[1] = bconv[nhalf * 64 + 32 + lm];
  const int cq = l >> 4;
  const int pxl = (nhalf << 4) + (l & 15);
  const float scale = (float)iwv / 256.0f;

#pragma unroll 1
  for (int mh = 0; mh < 2; ++mh) {
#pragma unroll 1
    for (int r = 0; r < 2; ++r) {
      if (mh || r) __syncthreads();
      if (mhalf == mh) {
#pragma unroll
        for (int ni = 0; ni < 2; ++ni)
#pragma unroll
          for (int rg = 0; rg < 16; ++rg) {
            int row = (rg & 3) + ((rg >> 2) << 3) + ((l >> 5) << 2);
            sm.tq[row][(nhalf << 6) + (ni << 5) + lm] =
                fmaxf((r ? acc[1][ni][rg] : acc[0][ni][rg]) + bcv[ni], 0.f);
          }
      }
      __syncthreads();
      if (mhalf == mh) {
        float tv[32];
#pragma unroll
        for (int i = 0; i < 8; ++i) {
          float4 t4 = *(const float4*)&sm.tq[pxl][(cq << 5) + (i << 2)];
          tv[i * 4 + 0] = t4.x; tv[i * 4 + 1] = t4.y;
          tv[i * 4 + 2] = t4.z; tv[i * 4 + 3] = t4.w;
        }
        float s19[19];
#pragma unroll
        for (int o = 0; o < 19; ++o) {
          const float* wh = (o < 18) ? (woff + o * 128) : wlog;
          const float4* w4 = (const float4*)(wh + (cq << 5));
          float a0 = 0.f;
#pragma unroll
          for (int i = 0; i < 8; ++i) {
            float4 wv4 = w4[i];
            a0 = fmaf(tv[i * 4 + 0], wv4.x, a0);
            a0 = fmaf(tv[i * 4 + 1], wv4.y, a0);
            a0 = fmaf(tv[i * 4 + 2], wv4.z, a0);
            a0 = fmaf(tv[i * 4 + 3], wv4.w, a0);
          }
          s19[o] = a0;
        }
#pragma unroll
        for (int o = 0; o < 19; ++o) {
          s19[o] += __shfl_xor(s19[o], 16, 64);
          s19[o] += __shfl_xor(s19[o], 32, 64);
        }
        if (cq == 0) {
          int bpx = (mh << 6) + (r << 5) + pxl;
          int ph = bpx >> 4, pw = bpx & 15;
          int gh = by * 8 + ph, gw = bx * 16 + pw;
          float sc = s19[18] + blog[0];
          // xs_lin uses linspace(0,image_h-1,Wf) indexed by w; ys_lin uses image_w, indexed by h
          float xv = (float)((double)gw * ((double)(ihv - 1) / 255.0));
          float yv = (float)((double)gh * ((double)(iwv - 1) / 255.0));
          float mnx = __builtin_inff(), mny = __builtin_inff();
          float mxx = -__builtin_inff(), mxy = -__builtin_inff();
#pragma unroll
          for (int p = 0; p < 9; ++p) {
            float ox = expf((s19[2 * p] + boff[2 * p]) * scale) - 1.f + xv;
            float oy = expf((s19[2 * p + 1] + boff[2 * p + 1]) * scale) - 1.f + yv;
            float cx2 = fminf(fmaxf(ox, 0.f), (float)(iwv - 1));
            float cy2 = fminf(fmaxf(oy, 0.f), (float)(ihv - 1));
            mnx = fminf(mnx, cx2); mxx = fmaxf(mxx, cx2);
            mny = fminf(mny, cy2); mxy = fmaxf(mxy, cy2);
          }
          size_t pix = (size_t)n * 65536 + (size_t)gh * 256 + gw;
          float* rec = out + pix * 5;
          rec[0] = sc; rec[1] = mnx; rec[2] = mny; rec[3] = mxx; rec[4] = mxy;
          if (scarr) scarr[pix] = sc;
          atomicAdd(&hist[n * 4096 + (fkey(sc) >> 20)], 1u);
        }
      }
    }
  }
#undef STAGE_ISSUE
#undef STAGE_WRITE
}

// ---- find cutoff bin (rank PRE_K) ----
__global__ __launch_bounds__(256) void cutoffk(const u32* __restrict__ hist, u32* __restrict__ cut) {
  int n = blockIdx.x;
  const u32* h = hist + n * 4096;
  __shared__ u32 pre[256];
  int t = threadIdx.x;
  u32 s0 = 0;
  for (int k = 0; k < 16; ++k) s0 += h[4095 - (t * 16 + k)];
  pre[t] = s0;
  __syncthreads();
  for (int off = 1; off < 256; off <<= 1) {
    u32 add = (t >= off) ? pre[t - off] : 0u;
    __syncthreads();
    pre[t] += add;
    __syncthreads();
  }
  u32 incl = pre[t];
  u32 excl = incl - s0;
  if (incl >= (u32)PRE_K && excl < (u32)PRE_K) {
    u32 cum = excl;
    for (int k = 0; k < 16; ++k) {
      int b = 4095 - (t * 16 + k);
      cum += h[b];
      if (cum >= (u32)PRE_K) { cut[n] = ((u32)b) << 20; break; }
    }
  }
}

// ---- collect candidates >= cutoff (coalesced via scarr) ----
__global__ void collectk(const float* __restrict__ out, const float* __restrict__ scarr,
                         const u32* __restrict__ cut,
                         u32* __restrict__ cnt, u64* __restrict__ cand) {
  int e = blockIdx.x * 256 + threadIdx.x;
  int n = e >> 16;
  u32 pix = e & 65535;
  float sc = scarr ? scarr[e] : out[((size_t)n * 65536 + pix) * 5];
  u32 key = fkey(sc);
  if (key >= cut[n]) {
    u32 pos = atomicAdd(&cnt[n], 1u);
    if (pos < (u32)CAP)
      cand[(size_t)n * CAP + pos] = ((u64)key << 32) | (u64)(0xFFFFFFFFu - pix);
  }
}

// ---- O(m^2) rank selection of top-1000 (order-invariant, exact ties by idx) ----
__global__ __launch_bounds__(1024) void ranksel(const u64* __restrict__ cand, const u32* __restrict__ cnt,
                                                const float* __restrict__ out,
                                                float* __restrict__ tb, float* __restrict__ scs) {
  int n = blockIdx.x;
  int t = threadIdx.x;
  __shared__ u64 d[CAP];
  u32 m = cnt[n]; if (m > (u32)CAP) m = CAP;
  for (int i = t; i < (int)m; i += 1024) d[i] = cand[(size_t)n * CAP + i];
  __syncthreads();
  for (int i = t; i < (int)m; i += 1024) {
    u64 ki = d[i];
    u32 r = 0;
    for (u32 j = 0; j < m; ++j) r += (d[j] > ki) ? 1u : 0u;
    if (r < (u32)PRE_K) {
      u32 pix = 0xFFFFFFFFu - (u32)(ki & 0xFFFFFFFFull);
      const float* rec = out + ((size_t)n * 65536 + pix) * 5;
      float sc = rec[0];
      float b0 = rec[1], b1 = rec[2], b2 = rec[3], b3 = rec[4];
      bool valid = ((b2 - b0) >= 0.f) && ((b3 - b1) >= 0.f);
      scs[n * PRE_K + r] = valid ? sc : -__builtin_inff();
      float* tbp = tb + ((size_t)n * PRE_K + r) * 4;
      tbp[0] = b0; tbp[1] = b1; tbp[2] = b2; tbp[3] = b3;
    }
  }
}

// ---- pairwise IoU suppression bitmasks; grid (colchunk=16, n=2) ----
__global__ __launch_bounds__(1024) void maskk(const float* __restrict__ tb, u64* __restrict__ maskw) {
  int c = blockIdx.x;
  int n = blockIdx.y;
  int t = threadIdx.x;
  __shared__ float bx[PRE_K][4];
  for (int e = t; e < PRE_K * 4; e += 1024) ((float*)bx)[e] = tb[(size_t)n * PRE_K * 4 + e];
  __syncthreads();
  u64 accm = 0;
  if (t < PRE_K) {
    float x1 = bx[t][0], y1 = bx[t][1], x2 = bx[t][2], y2 = bx[t][3];
    float ai = (x2 - x1) * (y2 - y1);
    int j0 = max(t + 1, c * 64), j1 = min(PRE_K, c * 64 + 64);
    for (int j = j0; j < j1; ++j) {
      float u1 = bx[j][0], v1 = bx[j][1], u2 = bx[j][2], v2 = bx[j][3];
      float aj = (u2 - u1) * (v2 - v1);
      float iw = fminf(x2, u2) - fmaxf(x1, u1); iw = fmaxf(iw, 0.f);
      float ih = fminf(y2, v2) - fmaxf(y1, v1); ih = fmaxf(ih, 0.f);
      float inter = iw * ih;
      float iou = inter / (ai + aj - inter + 1e-9f);
      if (iou > 0.7f) accm |= (1ull << (j & 63));
    }
  }
  maskw[((size_t)n * 1024 + t) * 16 + c] = accm;
}

// ---- serial greedy scan (reg-prefetch from global) + stable partition ----
__global__ __launch_bounds__(64) void finalk(const u64* __restrict__ maskw,
                                             const float* __restrict__ scs,
                                             const float* __restrict__ tb,
                                             float* __restrict__ out) {
  int n = blockIdx.x;
  int lane = threadIdx.x;
  __shared__ float lsc[1024];
  __shared__ unsigned short ordA[1024];
  __shared__ unsigned short ordB[1024];
  for (int e = lane; e < 1024; e += 64)
    lsc[e] = (e < PRE_K) ? scs[n * PRE_K + e] : -__builtin_inff();
  __syncthreads();

  u64 sup = 0;
#pragma unroll
  for (int c = 0; c < 16; ++c) {
    u64 b = __ballot(!(lsc[c * 64 + lane] > -__builtin_inff()));
    if (lane == c) sup = b;
  }

  const u64* gm = maskw + (size_t)n * 1024 * 16;
  u64 pre[16];
#pragma unroll
  for (int d = 0; d < 16; ++d)
    pre[d] = (lane < 16) ? gm[d * 16 + lane] : 0ull;

  for (int i0 = 0; i0 < 1024; i0 += 16) {
#pragma unroll
    for (int d = 0; d < 16; ++d) {
      int i = i0 + d;
      u64 mi = pre[d];
      int nx = i + 16;
      pre[d] = (nx < 1024 && lane < 16) ? gm[(size_t)nx * 16 + lane] : 0ull;
      int w = i >> 6;
      u64 sw = shfl64(sup, w);
      bool supbit = (sw >> (i & 63)) & 1ull;
      if (!supbit) sup |= mi;
    }
  }

  u64 ltm = (1ull << lane) - 1ull;
  u32 baseA = 0, baseB = 0;
  for (int c = 0; c < 16; ++c) {
    int i = c * 64 + lane;
    u64 sw = shfl64(sup, c);
    bool bit = (sw >> lane) & 1ull;
    bool vi = i < PRE_K;
    bool sf = vi && !bit && (lsc[vi ? i : 0] > -__builtin_inff());
    u64 mA = __ballot(sf);
    u64 mB = __ballot(vi && !sf);
    if (sf) ordA[baseA + __popcll(mA & ltm)] = (unsigned short)i;
    else if (vi) ordB[baseB + __popcll(mB & ltm)] = (unsigned short)i;
    baseA += (u32)__popcll(mA);
    baseB += (u32)__popcll(mB);
  }
  __syncthreads();

  for (int r = 0; r < 4; ++r) {
    int k = r * 64 + lane;
    int fi; float v;
    if (k < (int)baseA) { fi = ordA[k]; v = lsc[fi]; }
    else { fi = ordB[k - baseA]; v = -__builtin_inff(); }
    const float* bp = tb + ((size_t)n * PRE_K + fi) * 4;
    float* kb = out + KB_OFF + ((size_t)n * 256 + k) * 4;
    kb[0] = bp[0]; kb[1] = bp[1]; kb[2] = bp[2]; kb[3] = bp[3];
    out[KS_OFF + (size_t)n * 256 + k] = v;
  }
}

extern "C" void kernel_launch(void* const* d_in, const int* in_sizes, int n_in,
                              void* d_out, int out_size, void* d_ws, size_t ws_size,
                              hipStream_t stream) {
  const float* x     = (const float*)d_in[0];
  const float* wc    = (const float*)d_in[1];
  const float* bconv = (const float*)d_in[2];
  const float* woff  = (const float*)d_in[3];
  const float* boff  = (const float*)d_in[4];
  const float* wlog  = (const float*)d_in[5];
  const float* blog  = (const float*)d_in[6];
  const int* ihp     = (const int*)d_in[7];
  const int* iwp     = (const int*)d_in[8];
  float* out = (float*)d_out;
  char* ws = (char*)d_ws;

  float* wf    = (float*)(ws + WF_OFF);
  u32* hist    = (u32*)(ws + HIST_OFF);
  u32* cnt     = (u32*)(ws + CNT_OFF);
  u32* cut     = (u32*)(ws + CUT_OFF);
  u64* cand    = (u64*)(ws + CAND_OFF);
  float* tb    = (float*)(ws + TB_OFF);
  float* scs   = (float*)(ws + SCS_OFF);
  u64* maskw   = (u64*)(ws + MASK_OFF);
  float* scarr = (ws_size >= WS_NEED) ? (float*)(ws + SCARR_OFF) : nullptr;

  hipLaunchKernelGGL(wsplitk, dim3(72), dim3(256), 0, stream, wc, wf, hist, cnt);
  hipLaunchKernelGGL(convk, dim3(16, 32, 2), dim3(256), 0, stream,
                     x, wf, bconv, woff, boff, wlog, blog, ihp, iwp, out, hist, scarr);
  hipLaunchKernelGGL(cutoffk, dim3(2), dim3(256), 0, stream, hist, cut);
  hipLaunchKernelGGL(collectk, dim3(512), dim3(256), 0, stream, out, scarr, cut, cnt, cand);
  hipLaunchKernelGGL(ranksel, dim3(2), dim3(1024), 0, stream, cand, cnt, out, tb, scs);
  hipLaunchKernelGGL(maskk, dim3(16, 2), dim3(1024), 0, stream, tb, maskw);
  hipLaunchKernelGGL(finalk, dim3(2), dim3(64), 0, stream, maskw, scs, tb, out);
}